// Round 14
// baseline (309.944 us; speedup 1.0000x reference)
//
#include <hip/hip_runtime.h>
#include <type_traits>

// TGV prox primal-dual, 30 iterations on (3,512,512) fp32.
// R14 = R13 (lean 2-iter fusion, 299.4us) + COALESCED U-STAGING:
//  - phase A0 stages u_prev rows -4..19 x cols -6..69 into su as 912
//    coalesced h8 loads/block (~3.6/thread), replacing phase A's 3960
//    masked scattered u-loads + phase B's 720 center loads.
//  - phases A and C share ONE LDS u-gather (4x aligned ds_read_b128/row,
//    unused lanes never consumed); tGlob deleted.
//  - phase B reads center-u from su and writes u_k IN PLACE (each thread
//    touches only its own strip's cells; rows 0,1,22,23 keep stale u_prev
//    which C provably never reads).
//  - su[24][76][4] f16 = 14.3 KB; total LDS 49.5 KB -> still 3 blocks/CU.
// All u round-trips through fp16 LDS are bit-exact -> bit-identical results.
// Ladder: R4 -3.6%, R5 -3.2%, R6 0%, R7 0%, R8 -6.6% (mask diet),
// R9 -12.6% (load/addr diet), R10 -1%, R11 +65% (reverted, VGPR lesson),
// R13 -9.6% (fusion; ~2.1us/launch measured). R3: never grid.sync (~200us/it).

#define H 512
#define W 512
#define C 3
#define HW (H * W)
#define CHW (C * H * W)
#define NPAIR 15

#define TW 64
#define TH 16

#define TAU     0.01f
#define LAM2    0.15f
#define RHO     1.99f
#define SIGMA   1.3888888888888888f   /* 1/TAU/72 */
#define TL1     0.001f                /* TAU*LAM1 */
#define INV_1PT (1.0f / 1.01f)        /* 1/(1+TAU) */

// sbA: xbar/rbar, rows -3..18 (idx rr+3, 22), cols idx c+8 (dim 78)
#define AR 22
#define AC 78
// sbB: xnew/rnew of iter k, rows -1..16 (idx rr+1, 18), cols idx c+4 (dim 72)
#define BR 18
#define BC 72
// su: u quads (4xf16/pixel), rows -4..19 (idx rr+4, 24), cols idx c+6 (dim 76)
#define UR 24
#define UC 76

typedef _Float16 f16;
typedef __attribute__((ext_vector_type(4))) _Float16 h4;   //  8B (one pixel quad)
typedef __attribute__((ext_vector_type(8))) _Float16 h8;   // 16B (two pixel quads)

// h-buffer layout (f16 units): [0, 2*CHW) = r interleaved (r0,r1) per pixel;
//                              [2*CHW, 6*CHW) = u interleaved (u0..u3) per pixel.

template <int MODE> // 0 = pair (1,2); 1 = middle pair; 2 = last pair (29,30)
__global__ __launch_bounds__(256)
void fused2(const float* __restrict__ y,
            const float* __restrict__ srcX,
            const f16*   __restrict__ srcH,
            float*       __restrict__ dstX,
            f16*         __restrict__ dstH,
            float*       __restrict__ outp)
{
    __shared__ float sbA[3][AR][AC];   // 20.6 KB
    __shared__ float sbB[3][BR][BC];   // 15.6 KB
    __shared__ f16   su[UR][UC][4];    // 14.3 KB

    const int tid = threadIdx.x;
    const int c   = blockIdx.z;
    const int i0  = blockIdx.y * TH;
    const int j0  = blockIdx.x * TW;
    const int cb  = c * HW;

    const bool edge = (MODE == 0) ||
                      (blockIdx.x == 0) || (blockIdx.x == W / TW - 1) ||
                      (blockIdx.y == 0) || (blockIdx.y == H / TH - 1);

    const f16* rSrc = srcH;            // (r0,r1) pairs
    const f16* uSrc = srcH + 2 * CHW;  // (u0..u3) quads
    f16* rDst = dstH;
    f16* uDst = dstH ? dstH + 2 * CHW : nullptr;

    // ---- phase A0: coalesced stage of u_prev into su ----
    if (MODE != 0) {
        if (!edge) {
            for (int t = tid; t < UR * 38; t += 256) {
                const int ur = t / 38;
                const int k  = t - ur * 38;
                const int gi = i0 + ur - 4;
                const int gc = j0 - 6 + 2 * k;          // even
                *(h8*)&su[ur][2 * k][0] =
                    *(const h8*)(uSrc + 4 * (cb + gi * W + gc));
            }
        } else {
            for (int t = tid; t < UR * 38; t += 256) {
                const int ur = t / 38;
                const int k  = t - ur * 38;
                const int gi = i0 + ur - 4;
                const int gc = j0 - 6 + 2 * k;
                const bool rok = (unsigned)gi < H;
                const bool ok0 = rok && ((unsigned)gc < W);
                const bool ok1 = rok && ((unsigned)(gc + 1) < W);
                if (ok0 && ok1) {
                    *(h8*)&su[ur][2 * k][0] =
                        *(const h8*)(uSrc + 4 * (cb + gi * W + gc));
                } else {
                    h4 a = {}, b = {};
                    if (ok0) a = *(const h4*)(uSrc + 4 * (cb + gi * W + gc));
                    if (ok1) b = *(const h4*)(uSrc + 4 * (cb + gi * W + gc + 1));
                    *(h4*)&su[ur][2 * k][0]     = a;
                    *(h4*)&su[ur][2 * k + 1][0] = b;
                }
            }
        }
        __syncthreads();
    }

    // ---- stage-1 prox core (masks only when !SAFE) ----
    auto prox1 = [&](auto SAFE_c, int gi, int gjb,
                     const float* yv, const float* x2c, const float* r0c, const float* r1c,
                     const float* t0c, const float* t1c, const float* t0n, const float* t1w,
                     float* xb, float* rb0, float* rb1,
                     float* xn, float* rn0, float* rn1) {
        constexpr bool SAFE = decltype(SAFE_c)::value;
        const bool imH = SAFE ? true : (gi < H - 1);
        #pragma unroll
        for (int e = 0; e < 4; ++e) {
            const int gj = gjb + e;
            const bool jmW = SAFE ? true : (gj < W - 1);
            const float nT  = t0n[e] - (imH ? t0c[e] : 0.f) + t1w[e] - (jmW ? t1c[e] : 0.f);
            const float xv  = (x2c[e] - nT + TAU * yv[e]) * INV_1PT;
            xb[e] = 2.f * xv - x2c[e];
            const float rp0 = r0c[e] + t0c[e];
            const float rp1 = r1c[e] + t1c[e];
            const float ss  = rp0 * rp0 + rp1 * rp1;
            const float f   = 1.f - fminf(TL1 * rsqrtf(ss), 1.f);
            const float rv0 = rp0 * f, rv1 = rp1 * f;
            rb0[e] = 2.f * rv0 - r0c[e];
            rb1[e] = 2.f * rv1 - r1c[e];
            xn[e]  = x2c[e] + RHO * (xv - x2c[e]);
            rn0[e] = r0c[e] + RHO * (rv0 - r0c[e]);
            rn1[e] = r1c[e] + RHO * (rv1 - r1c[e]);
        }
    };

    // ---- u-row readers from su (aligned h8 reads; unused lanes never consumed)
    // uRow6: cols s-1..s+4 (index 0..5) of row ur, all 4 components.
    auto uRow6 = [&](int ur, int s, float* u0, float* u1, float* u2, float* u3) {
        const h8 q0 = *(const h8*)&su[ur][s + 4][0];   // cols s-2, s-1
        const h8 q1 = *(const h8*)&su[ur][s + 6][0];   // cols s,   s+1
        const h8 q2 = *(const h8*)&su[ur][s + 8][0];   // cols s+2, s+3
        const h8 q3 = *(const h8*)&su[ur][s + 10][0];  // cols s+4, s+5
        u0[0]=(float)q0[4]; u1[0]=(float)q0[5]; u2[0]=(float)q0[6]; u3[0]=(float)q0[7];
        u0[1]=(float)q1[0]; u1[1]=(float)q1[1]; u2[1]=(float)q1[2]; u3[1]=(float)q1[3];
        u0[2]=(float)q1[4]; u1[2]=(float)q1[5]; u2[2]=(float)q1[6]; u3[2]=(float)q1[7];
        u0[3]=(float)q2[0]; u1[3]=(float)q2[1]; u2[3]=(float)q2[2]; u3[3]=(float)q2[3];
        u0[4]=(float)q2[4]; u1[4]=(float)q2[5]; u2[4]=(float)q2[6]; u3[4]=(float)q2[7];
        u0[5]=(float)q3[0]; u1[5]=(float)q3[1]; u2[5]=(float)q3[2]; u3[5]=(float)q3[3];
    };
    // uRow4u0: component 0 only, cols s..s+3 (for u0s).
    auto uRow4u0 = [&](int ur, int s, float* u0) {
        const h8 q1 = *(const h8*)&su[ur][s + 6][0];
        const h8 q2 = *(const h8*)&su[ur][s + 8][0];
        u0[0]=(float)q1[0]; u0[1]=(float)q1[4]; u0[2]=(float)q2[0]; u0[3]=(float)q2[4];
    };

    // ---- t-terms from su (shared by phases A and C) ----
    auto tLds = [&](auto SAFE_c, int rr, int s, int gi, int gjb,
                    float* t0c, float* t1c, float* t0n, float* t1w) {
        constexpr bool SAFE = decltype(SAFE_c)::value;
        float N0[6], N1[6], N2[6], N3[6];
        float C0[6], C1[6], C2[6], C3[6];
        float S0[4];
        uRow6(rr + 3, s, N0, N1, N2, N3);
        uRow6(rr + 4, s, C0, C1, C2, C3);
        uRow4u0(rr + 5, s, S0);
        // mapping: u0c[e]=C0[e+1], u1c[k]=C1[k+1], u2r[k]=C2[k], u3c[k]=C3[k],
        //          u0n[e]=N0[e+1], u1n[k]=N1[k+1], u3n[k]=N3[k], u0s[e]=S0[e]
        if constexpr (SAFE) {
            #pragma unroll
            for (int e = 0; e < 4; ++e) {
                t0c[e] = TAU * (C0[e + 1] - S0[e] + C1[e + 1] - C1[e + 2]);
                t1c[e] = TAU * (C2[e + 1] - C2[e + 2] + N3[e + 1] - C3[e + 1]);
                t0n[e] = TAU * (N0[e + 1] - C0[e + 1] + N1[e + 1] - N1[e + 2]);
                t1w[e] = TAU * (C2[e] - C2[e + 1] + N3[e] - C3[e]);
            }
        } else {
            const bool im0 = gi > 0, imHl = gi < H - 1;
            #pragma unroll
            for (int e = 0; e < 4; ++e) {
                const int gj = gjb + e;
                const bool jm0 = gj > 0;
                t0c[e] = TAU * (C0[e + 1] - S0[e] + (jm0 ? C1[e + 1] : 0.f) - C1[e + 2]);
                t1c[e] = TAU * (C2[e + 1] - C2[e + 2] + N3[e + 1] - (imHl ? C3[e + 1] : 0.f));
                t0n[e] = im0 ? TAU * (N0[e + 1] - C0[e + 1] + (jm0 ? N1[e + 1] : 0.f) - N1[e + 2]) : 0.f;
                t1w[e] = jm0 ? TAU * (C2[e] - C2[e + 1] + N3[e] - (imHl ? C3[e] : 0.f)) : 0.f;
            }
        }
    };

    // ---- sbA stencil loader (shared by phases B and D) ----
    auto loadA = [&](int rr, int s,
                     float* xA, float* xS, float* xN,
                     float* r0C, float* r0N, float* r1C, float* r1S) {
        const int lr = rr + 3, lc = s + 8;
        float4 v;
        xA[0] = sbA[0][lr][lc - 1];
        v = *(const float4*)&sbA[0][lr][lc]; xA[1]=v.x; xA[2]=v.y; xA[3]=v.z; xA[4]=v.w;
        xA[5] = sbA[0][lr][lc + 4];
        xS[0] = sbA[0][lr + 1][lc - 1];
        v = *(const float4*)&sbA[0][lr + 1][lc]; xS[1]=v.x; xS[2]=v.y; xS[3]=v.z; xS[4]=v.w;
        xS[5] = sbA[0][lr + 1][lc + 4];
        v = *(const float4*)&sbA[0][lr - 1][lc]; xN[0]=v.x; xN[1]=v.y; xN[2]=v.z; xN[3]=v.w;
        r0C[0] = sbA[1][lr][lc - 1];
        v = *(const float4*)&sbA[1][lr][lc]; r0C[1]=v.x; r0C[2]=v.y; r0C[3]=v.z; r0C[4]=v.w;
        v = *(const float4*)&sbA[1][lr - 1][lc]; r0N[0]=v.x; r0N[1]=v.y; r0N[2]=v.z; r0N[3]=v.w;
        r1C[0] = sbA[2][lr][lc - 1];
        v = *(const float4*)&sbA[2][lr][lc]; r1C[1]=v.x; r1C[2]=v.y; r1C[3]=v.z; r1C[4]=v.w;
        v = *(const float4*)&sbA[2][lr + 1][lc]; r1S[0]=v.x; r1S[1]=v.y; r1S[2]=v.z; r1S[3]=v.w;
    };

    // ---- stage-2 core (shared by phases B and D) ----
    auto s2core = [&](auto SAFE_c, int gi, int gjb,
                      const float* xA, const float* xS, const float* xN,
                      const float* r0C, const float* r0N, const float* r1C, const float* r1S,
                      const float* cu0, const float* cu1, const float* cu2, const float* cu3,
                      float* un0, float* un1, float* un2, float* un3) {
        constexpr bool SAFE = decltype(SAFE_c)::value;
        const bool im0 = SAFE ? true : (gi > 0);
        const bool imH = SAFE ? true : (gi < H - 1);
        #pragma unroll
        for (int e = 0; e < 4; ++e) {
            const int gj = gjb + e;
            const bool jm0 = SAFE ? true : (gj > 0);
            const bool jmW = SAFE ? true : (gj < W - 1);
            const float xC = xA[e + 1], xE = xA[e + 2], xW_ = xA[e];
            const float I0c = (imH ? xS[e + 1] - xC : 0.f) - r0C[e + 1];
            const float I0n = im0 ? (xC - xN[e] - r0N[e]) : 0.f;
            const float I0w = jm0 ? ((imH ? xS[e] - xW_ : 0.f) - r0C[e]) : 0.f;
            const float I1c = (jmW ? xE - xC : 0.f) - r1C[e + 1];
            const float I1w = jm0 ? (xC - xW_ - r1C[e]) : 0.f;
            const float I1s = imH ? ((jmW ? xS[e + 2] - xS[e + 1] : 0.f) - r1S[e]) : 0.f;
            const float g0 = I0c - I0n;
            const float g1 = jm0 ? (I0c - I0w) : 0.f;
            const float g2 = I1c - I1w;
            const float g3 = imH ? (I1s - I1c) : 0.f;
            const float up0 = cu0[e] + SIGMA * g0;
            const float up1 = cu1[e] + SIGMA * g1;
            const float up2 = cu2[e] + SIGMA * g2;
            const float up3 = cu3[e] + SIGMA * g3;
            const float ss  = up0 * up0 + up1 * up1 + up2 * up2 + up3 * up3;
            const float inv = fminf(LAM2 * rsqrtf(ss), 1.f);
            un0[e] = cu0[e] + RHO * (up0 * inv - cu0[e]);
            un1[e] = cu1[e] + RHO * (up1 * inv - cu1[e]);
            un2[e] = cu2[e] + RHO * (up2 * inv - cu2[e]);
            un3[e] = cu3[e] + RHO * (up3 * inv - cu3[e]);
        }
    };

    // ---- center-u reader from su ----
    auto cuRead = [&](int rr, int s, float* cu0, float* cu1, float* cu2, float* cu3) {
        const h8 a = *(const h8*)&su[rr + 4][s + 6][0];
        const h8 b = *(const h8*)&su[rr + 4][s + 8][0];
        cu0[0]=(float)a[0]; cu1[0]=(float)a[1]; cu2[0]=(float)a[2]; cu3[0]=(float)a[3];
        cu0[1]=(float)a[4]; cu1[1]=(float)a[5]; cu2[1]=(float)a[6]; cu3[1]=(float)a[7];
        cu0[2]=(float)b[0]; cu1[2]=(float)b[1]; cu2[2]=(float)b[2]; cu3[2]=(float)b[3];
        cu0[3]=(float)b[4]; cu1[3]=(float)b[5]; cu2[3]=(float)b[6]; cu3[3]=(float)b[7];
    };

    // ================= phase A: stage-1 of iter k, rows -3..18 =================
    auto phaseA = [&](auto SAFE_c) {
        constexpr bool SAFE = decltype(SAFE_c)::value;
        for (int idx = tid; idx < AR * 18; idx += 256) {
            const int rw = idx / 18, rr = rw - 3;
            const int s  = 4 * (idx - rw * 18) - 4;
            const int gi = i0 + rr, gjb = j0 + s;
            const int p  = cb + gi * W + gjb;
            const bool rowC  = SAFE || ((unsigned)gi < H);
            const bool cMain = SAFE || ((unsigned)gjb < W);
            const bool okC   = rowC && cMain;

            float yv[4], x2c[4], r0c[4], r1c[4];
            if (okC) { *(float4*)yv = *(const float4*)(y + p); }
            else     { yv[0] = yv[1] = yv[2] = yv[3] = 0.f; }

            float t0c[4], t1c[4], t0n[4], t1w[4];
            if (MODE == 0) {
                #pragma unroll
                for (int e = 0; e < 4; ++e) {
                    x2c[e] = yv[e]; r0c[e] = 0.f; r1c[e] = 0.f;
                    t0c[e] = t1c[e] = t0n[e] = t1w[e] = 0.f;
                }
            } else {
                if (okC) {
                    *(float4*)x2c = *(const float4*)(srcX + p);
                    const h8 rv = *(const h8*)(rSrc + 2 * p);
                    #pragma unroll
                    for (int e = 0; e < 4; ++e) {
                        r0c[e] = (float)rv[2 * e];
                        r1c[e] = (float)rv[2 * e + 1];
                    }
                } else {
                    #pragma unroll
                    for (int e = 0; e < 4; ++e) { x2c[e] = 0.f; r0c[e] = 0.f; r1c[e] = 0.f; }
                }
                tLds(SAFE_c, rr, s, gi, gjb, t0c, t1c, t0n, t1w);
            }

            float xb[4], rb0[4], rb1[4], xn[4], rn0[4], rn1[4];
            prox1(SAFE_c, gi, gjb, yv, x2c, r0c, r1c, t0c, t1c, t0n, t1w,
                  xb, rb0, rb1, xn, rn0, rn1);

            *(float4*)&sbA[0][rr + 3][s + 8] = *(float4*)xb;
            *(float4*)&sbA[1][rr + 3][s + 8] = *(float4*)rb0;
            *(float4*)&sbA[2][rr + 3][s + 8] = *(float4*)rb1;
            if (rr >= -1 && rr <= 16) {
                *(float4*)&sbB[0][rr + 1][s + 4] = *(float4*)xn;
                *(float4*)&sbB[1][rr + 1][s + 4] = *(float4*)rn0;
                *(float4*)&sbB[2][rr + 1][s + 4] = *(float4*)rn1;
            }
            // no global stores: iter-k x/r live only in LDS
        }
    };

    // ================= phase B: stage-2 of iter k, rows -2..17 -> su (in place)
    auto phaseB = [&](auto SAFE_c) {
        constexpr bool SAFE = decltype(SAFE_c)::value;
        for (int idx = tid; idx < 20 * 18; idx += 256) {
            const int rw = idx / 18, rr = rw - 2;
            const int s  = 4 * (idx - rw * 18) - 4;
            const int gi = i0 + rr, gjb = j0 + s;

            float xA[6], xS[6], xN[4], r0C[5], r0N[4], r1C[5], r1S[4];
            loadA(rr, s, xA, xS, xN, r0C, r0N, r1C, r1S);

            float cu0[4], cu1[4], cu2[4], cu3[4];
            if (MODE == 0) {
                #pragma unroll
                for (int e = 0; e < 4; ++e) { cu0[e] = cu1[e] = cu2[e] = cu3[e] = 0.f; }
            } else {
                cuRead(rr, s, cu0, cu1, cu2, cu3);  // staged u_prev (0 for OOI)
            }

            float un0[4], un1[4], un2[4], un3[4];
            s2core(SAFE_c, gi, gjb, xA, xS, xN, r0C, r0N, r1C, r1S,
                   cu0, cu1, cu2, cu3, un0, un1, un2, un3);

            // in-place u_k write (own cells only; OOI pixels must store 0)
            const int ur = rr + 4, uc = s + 6;
            if constexpr (SAFE) {
                h8 w0, w1;
                #pragma unroll
                for (int e = 0; e < 2; ++e) {
                    w0[4*e+0]=(f16)un0[e]; w0[4*e+1]=(f16)un1[e];
                    w0[4*e+2]=(f16)un2[e]; w0[4*e+3]=(f16)un3[e];
                }
                #pragma unroll
                for (int e = 2; e < 4; ++e) {
                    w1[4*(e-2)+0]=(f16)un0[e]; w1[4*(e-2)+1]=(f16)un1[e];
                    w1[4*(e-2)+2]=(f16)un2[e]; w1[4*(e-2)+3]=(f16)un3[e];
                }
                *(h8*)&su[ur][uc][0]     = w0;
                *(h8*)&su[ur][uc + 2][0] = w1;
            } else {
                #pragma unroll
                for (int e = 0; e < 4; ++e) {
                    const int gj = gjb + e;
                    const bool ok = ((unsigned)gi < H) && ((unsigned)gj < W);
                    h4 hv = {};
                    if (ok) { hv[0]=(f16)un0[e]; hv[1]=(f16)un1[e]; hv[2]=(f16)un2[e]; hv[3]=(f16)un3[e]; }
                    *(h4*)&su[ur][uc + e][0] = hv;
                }
            }
        }
    };

    // ================= phase C: stage-1 of iter k+1, rows -1..16 ===============
    auto phaseC = [&](auto SAFE_c) {
        constexpr bool SAFE = decltype(SAFE_c)::value;
        for (int idx = tid; idx < BR * 18; idx += 256) {
            const int rw = idx / 18, rr = rw - 1;
            const int s  = 4 * (idx - rw * 18) - 4;
            const int gi = i0 + rr, gjb = j0 + s;
            const int p  = cb + gi * W + gjb;
            const bool okC = SAFE || (((unsigned)gi < H) && ((unsigned)gjb < W));

            float yv[4];
            if (okC) { *(float4*)yv = *(const float4*)(y + p); }
            else     { yv[0] = yv[1] = yv[2] = yv[3] = 0.f; }

            float x2c[4], r0c[4], r1c[4];
            *(float4*)x2c = *(const float4*)&sbB[0][rr + 1][s + 4];
            *(float4*)r0c = *(const float4*)&sbB[1][rr + 1][s + 4];
            *(float4*)r1c = *(const float4*)&sbB[2][rr + 1][s + 4];

            float t0c[4], t1c[4], t0n[4], t1w[4];
            tLds(SAFE_c, rr, s, gi, gjb, t0c, t1c, t0n, t1w);

            float xb[4], rb0[4], rb1[4], xn[4], rn0[4], rn1[4];
            prox1(SAFE_c, gi, gjb, yv, x2c, r0c, r1c, t0c, t1c, t0n, t1w,
                  xb, rb0, rb1, xn, rn0, rn1);

            *(float4*)&sbA[0][rr + 3][s + 8] = *(float4*)xb;
            *(float4*)&sbA[1][rr + 3][s + 8] = *(float4*)rb0;
            *(float4*)&sbA[2][rr + 3][s + 8] = *(float4*)rb1;

            if ((unsigned)rr < 16 && (unsigned)s < 64) { // interior strip
                if (MODE == 2) {
                    *(float4*)(outp + p) = *(float4*)xn;
                    *(float4*)(outp + CHW + 2 * p)     = make_float4(rn0[0], rn1[0], rn0[1], rn1[1]);
                    *(float4*)(outp + CHW + 2 * p + 4) = make_float4(rn0[2], rn1[2], rn0[3], rn1[3]);
                } else {
                    *(float4*)(dstX + p) = *(float4*)xn;
                    h8 hr;
                    #pragma unroll
                    for (int e = 0; e < 4; ++e) {
                        hr[2 * e]     = (f16)rn0[e];
                        hr[2 * e + 1] = (f16)rn1[e];
                    }
                    *(h8*)(rDst + 2 * p) = hr;
                }
            }
        }
    };

    // ---- run phases (sbA/su WAR hazards covered by inter-phase barriers) ----
    if (!edge) phaseA(std::true_type{});  else phaseA(std::false_type{});
    __syncthreads();
    if (!edge) phaseB(std::true_type{});  else phaseB(std::false_type{});
    __syncthreads();
    if (!edge) phaseC(std::true_type{});  else phaseC(std::false_type{});
    __syncthreads();

    // ================= phase D: stage-2 of iter k+1, interior ==================
    {
        const int rr = tid >> 4;
        const int s  = 4 * (tid & 15);
        const int gi = i0 + rr, gjb = j0 + s;
        const int p  = cb + gi * W + gjb;

        float xA[6], xS[6], xN[4], r0C[5], r0N[4], r1C[5], r1S[4];
        loadA(rr, s, xA, xS, xN, r0C, r0N, r1C, r1S);

        float cu0[4], cu1[4], cu2[4], cu3[4];
        cuRead(rr, s, cu0, cu1, cu2, cu3);   // u_k written by phase B

        float un0[4], un1[4], un2[4], un3[4];
        if (!edge)
            s2core(std::true_type{},  gi, gjb, xA, xS, xN, r0C, r0N, r1C, r1S,
                   cu0, cu1, cu2, cu3, un0, un1, un2, un3);
        else
            s2core(std::false_type{}, gi, gjb, xA, xS, xN, r0C, r0N, r1C, r1S,
                   cu0, cu1, cu2, cu3, un0, un1, un2, un3);

        if (MODE == 2) {
            #pragma unroll
            for (int e = 0; e < 4; ++e)
                *(float4*)(outp + 3 * CHW + 4 * (p + e)) =
                    make_float4(un0[e], un1[e], un2[e], un3[e]);
        } else {
            h8 w0, w1;
            #pragma unroll
            for (int e = 0; e < 2; ++e) {
                w0[4*e+0]=(f16)un0[e]; w0[4*e+1]=(f16)un1[e];
                w0[4*e+2]=(f16)un2[e]; w0[4*e+3]=(f16)un3[e];
            }
            #pragma unroll
            for (int e = 2; e < 4; ++e) {
                w1[4*(e-2)+0]=(f16)un0[e]; w1[4*(e-2)+1]=(f16)un1[e];
                w1[4*(e-2)+2]=(f16)un2[e]; w1[4*(e-2)+3]=(f16)un3[e];
            }
            *(h8*)(uDst + 4 * p)     = w0;
            *(h8*)(uDst + 4 * p + 8) = w1;
        }
    }
}

extern "C" void kernel_launch(void* const* d_in, const int* in_sizes, int n_in,
                              void* d_out, int out_size, void* d_ws, size_t ws_size,
                              hipStream_t stream) {
    const float* y = (const float*)d_in[0];
    float* out = (float*)d_out;

    // ws layout: x2 fp32 buf0 | x2 fp32 buf1 | h-buf0 (6*CHW f16) | h-buf1
    float* x0 = (float*)d_ws;
    float* x1 = x0 + CHW;
    f16*   h0 = (f16*)(x1 + CHW);
    f16*   h1 = h0 + 6 * CHW;

    dim3 blk(256, 1, 1);
    dim3 grd(W / TW, H / TH, C);    // (8, 32, 3) = 768 blocks

    // 15 fused launches: pairs (1,2),(3,4),...,(29,30)
    fused2<0><<<grd, blk, 0, stream>>>(y, nullptr, nullptr, x0, h0, nullptr);
    for (int i = 1; i < NPAIR - 1; ++i) {
        const bool even = (i % 2 == 0);
        float* sx = even ? x1 : x0;  f16* sh = even ? h1 : h0;
        float* dx = even ? x0 : x1;  f16* dh = even ? h0 : h1;
        fused2<1><<<grd, blk, 0, stream>>>(y, sx, sh, dx, dh, nullptr);
    }
    // pair 15 (iters 29,30): src = dst of pair 14 (i=13, odd -> x1/h1)
    fused2<2><<<grd, blk, 0, stream>>>(y, x1, h1, nullptr, nullptr, out);
}

// Round 15
// 299.987 us; speedup vs baseline: 1.0332x; 1.0332x over previous
//
#include <hip/hip_runtime.h>
#include <type_traits>

// TGV prox primal-dual, 30 iterations on (3,512,512) fp32.
// R15 = REVERT TO R13 (best verified: 299.4us). R14's coalesced u-staging
// regressed +3.5%: the scattered u-loads it replaced were L2-resident and
// latency-hidden; staging added a phase + barrier + LDS round-trip of equal
// chain length. Instruction-diet lever is closed (last three variants:
// -1%, +65%, +3.5%).
// Final ladder: R4 bytes x0.6 -> -3.6%; R5 occ x2 -> -3.2%; R6 fusion(fat) 0%;
// R7 epochs/barriers halved -> 0%; R8 mask-free interior -> -6.6%;
// R9 interleaved state -> -12.6%; R10 -1%; R11 row-pair VGPR blowup -> +65%
// (reverted); R13 lean fusion -> -9.6% (~2.1us/launch measured); R14 staging
// -> +3.5% (reverted). 434.6 -> 299.4us total (-31%).
// Structure: per pair, phase A (s1 iter k, rows -3..18, u DIRECT from global)
// -> sbA+sbB; phase B (s2 iter k, rows -2..17) -> u_k in LDS (OOI pixels 0);
// phase C (s1 iter k+1, u from LDS, x2/r from sbB) -> sbA + global x/r;
// phase D (s2 iter k+1, interior) -> global u.
// R3: never grid.sync on this chip (~200us/iter).

#define H 512
#define W 512
#define C 3
#define HW (H * W)
#define CHW (C * H * W)
#define NPAIR 15

#define TW 64
#define TH 16

#define TAU     0.01f
#define LAM2    0.15f
#define RHO     1.99f
#define SIGMA   1.3888888888888888f   /* 1/TAU/72 */
#define TL1     0.001f                /* TAU*LAM1 */
#define INV_1PT (1.0f / 1.01f)        /* 1/(1+TAU) */

// sbA: xbar/rbar, rows -3..18 (idx rr+3, 22), cols -5..68 (idx c+8, dim 78)
#define AR 22
#define AC 78
// sbB: xnew/rnew of iter k, rows -1..16 (idx rr+1, 18), cols -4..67 (idx c+4)
#define BR 18
#define BC 72
// su: u_k, 4xf16 per pixel, rows -2..17 (idx rr+2, 20), cols -5..68 (idx c+6)
#define UR 20
#define UC 75

typedef _Float16 f16;
typedef __attribute__((ext_vector_type(4))) _Float16 h4;   //  8B
typedef __attribute__((ext_vector_type(8))) _Float16 h8;   // 16B

// h-buffer layout (f16 units): [0, 2*CHW) = r interleaved (r0,r1) per pixel;
//                              [2*CHW, 6*CHW) = u interleaved (u0..u3) per pixel.

template <int MODE> // 0 = pair (1,2); 1 = middle pair; 2 = last pair (29,30)
__global__ __launch_bounds__(256)
void fused2(const float* __restrict__ y,
            const float* __restrict__ srcX,
            const f16*   __restrict__ srcH,
            float*       __restrict__ dstX,
            f16*         __restrict__ dstH,
            float*       __restrict__ outp)
{
    __shared__ float sbA[3][AR][AC];   // 20.6 KB
    __shared__ float sbB[3][BR][BC];   // 15.6 KB
    __shared__ f16   su[UR][UC][4];    // 11.7 KB

    const int tid = threadIdx.x;
    const int c   = blockIdx.z;
    const int i0  = blockIdx.y * TH;
    const int j0  = blockIdx.x * TW;
    const int cb  = c * HW;

    const bool edge = (MODE == 0) ||
                      (blockIdx.x == 0) || (blockIdx.x == W / TW - 1) ||
                      (blockIdx.y == 0) || (blockIdx.y == H / TH - 1);

    const f16* rSrc = srcH;            // (r0,r1) pairs
    const f16* uSrc = srcH + 2 * CHW;  // (u0..u3) quads
    f16* rDst = dstH;
    f16* uDst = dstH ? dstH + 2 * CHW : nullptr;

    // ---- stage-1 prox core (masks only when !SAFE) ----
    auto prox1 = [&](auto SAFE_c, int gi, int gjb,
                     const float* yv, const float* x2c, const float* r0c, const float* r1c,
                     const float* t0c, const float* t1c, const float* t0n, const float* t1w,
                     float* xb, float* rb0, float* rb1,
                     float* xn, float* rn0, float* rn1) {
        constexpr bool SAFE = decltype(SAFE_c)::value;
        const bool imH = SAFE ? true : (gi < H - 1);
        #pragma unroll
        for (int e = 0; e < 4; ++e) {
            const int gj = gjb + e;
            const bool jmW = SAFE ? true : (gj < W - 1);
            const float nT  = t0n[e] - (imH ? t0c[e] : 0.f) + t1w[e] - (jmW ? t1c[e] : 0.f);
            const float xv  = (x2c[e] - nT + TAU * yv[e]) * INV_1PT;
            xb[e] = 2.f * xv - x2c[e];
            const float rp0 = r0c[e] + t0c[e];
            const float rp1 = r1c[e] + t1c[e];
            const float ss  = rp0 * rp0 + rp1 * rp1;
            const float f   = 1.f - fminf(TL1 * rsqrtf(ss), 1.f);
            const float rv0 = rp0 * f, rv1 = rp1 * f;
            rb0[e] = 2.f * rv0 - r0c[e];
            rb1[e] = 2.f * rv1 - r1c[e];
            xn[e]  = x2c[e] + RHO * (xv - x2c[e]);
            rn0[e] = r0c[e] + RHO * (rv0 - r0c[e]);
            rn1[e] = r1c[e] + RHO * (rv1 - r1c[e]);
        }
    };

    // ---- t-terms from GLOBAL u (phase A; R12's proven gather) ----
    auto tGlob = [&](auto SAFE_c, int gi, int gjb, int p,
                     float* t0c, float* t1c, float* t0n, float* t1w) {
        constexpr bool SAFE = decltype(SAFE_c)::value;
        const bool rowC  = SAFE || ((unsigned)gi < H);
        const bool cMain = SAFE || ((unsigned)gjb < W);
        const bool okC   = rowC && cMain;
        const bool rowN = SAFE || ((unsigned)(gi - 1) < H);
        const bool rowS = SAFE || ((unsigned)(gi + 1) < H);
        const bool cm1  = SAFE || ((unsigned)(gjb - 1) < W);
        const bool c4   = SAFE || ((unsigned)(gjb + 4) < W);
        const int pN = p - W, pS = p + W;
        auto L4 = [&](int pp, bool ok) -> h4 { h4 z = {}; if (ok) z = *(const h4*)(uSrc + 4 * pp); return z; };
        auto L8 = [&](int pp, bool ok) -> h8 { h8 z = {}; if (ok) z = *(const h8*)(uSrc + 4 * pp); return z; };
        const h4 nA = L4(pN - 1, rowN && cm1);
        const h8 nB = L8(pN,     rowN && cMain);
        const h8 nC = L8(pN + 2, rowN && cMain);
        const h4 nD = L4(pN + 4, rowN && c4);
        const h4 cA = L4(p - 1,  rowC && cm1);
        const h8 cB = L8(p,      okC);
        const h8 cC = L8(p + 2,  okC);
        const h4 cD = L4(p + 4,  rowC && c4);
        const h8 sB = L8(pS,     rowS && cMain);
        const h8 sC = L8(pS + 2, rowS && cMain);

        const float u0c[4] = {(float)cB[0], (float)cB[4], (float)cC[0], (float)cC[4]};
        const float u1c[5] = {(float)cB[1], (float)cB[5], (float)cC[1], (float)cC[5], (float)cD[1]};
        const float u2r[6] = {(float)cA[2], (float)cB[2], (float)cB[6], (float)cC[2], (float)cC[6], (float)cD[2]};
        const float u3c[5] = {(float)cA[3], (float)cB[3], (float)cB[7], (float)cC[3], (float)cC[7]};
        const float u0n[4] = {(float)nB[0], (float)nB[4], (float)nC[0], (float)nC[4]};
        const float u1n[5] = {(float)nB[1], (float)nB[5], (float)nC[1], (float)nC[5], (float)nD[1]};
        const float u3n[5] = {(float)nA[3], (float)nB[3], (float)nB[7], (float)nC[3], (float)nC[7]};
        const float u0s[4] = {(float)sB[0], (float)sB[4], (float)sC[0], (float)sC[4]};

        if constexpr (SAFE) {
            #pragma unroll
            for (int e = 0; e < 4; ++e) {
                t0c[e] = TAU * (u0c[e] - u0s[e] + u1c[e] - u1c[e + 1]);
                t1c[e] = TAU * (u2r[e + 1] - u2r[e + 2] + u3n[e + 1] - u3c[e + 1]);
                t0n[e] = TAU * (u0n[e] - u0c[e] + u1n[e] - u1n[e + 1]);
                t1w[e] = TAU * (u2r[e] - u2r[e + 1] + u3n[e] - u3c[e]);
            }
        } else {
            const bool im0 = gi > 0, imHl = gi < H - 1;
            #pragma unroll
            for (int e = 0; e < 4; ++e) {
                const int gj = gjb + e;
                const bool jm0 = gj > 0;
                t0c[e] = TAU * (u0c[e] - u0s[e] + (jm0 ? u1c[e] : 0.f) - u1c[e + 1]);
                t1c[e] = TAU * (u2r[e + 1] - u2r[e + 2] + u3n[e + 1] - (imHl ? u3c[e + 1] : 0.f));
                t0n[e] = im0 ? TAU * (u0n[e] - u0c[e] + (jm0 ? u1n[e] : 0.f) - u1n[e + 1]) : 0.f;
                t1w[e] = jm0 ? TAU * (u2r[e] - u2r[e + 1] + u3n[e] - (imHl ? u3c[e] : 0.f)) : 0.f;
            }
        }
    };

    // ---- sbA stencil loader (shared by phases B and D) ----
    auto loadA = [&](int rr, int s,
                     float* xA, float* xS, float* xN,
                     float* r0C, float* r0N, float* r1C, float* r1S) {
        const int lr = rr + 3, lc = s + 8;
        float4 v;
        xA[0] = sbA[0][lr][lc - 1];
        v = *(const float4*)&sbA[0][lr][lc]; xA[1]=v.x; xA[2]=v.y; xA[3]=v.z; xA[4]=v.w;
        xA[5] = sbA[0][lr][lc + 4];
        xS[0] = sbA[0][lr + 1][lc - 1];
        v = *(const float4*)&sbA[0][lr + 1][lc]; xS[1]=v.x; xS[2]=v.y; xS[3]=v.z; xS[4]=v.w;
        xS[5] = sbA[0][lr + 1][lc + 4];
        v = *(const float4*)&sbA[0][lr - 1][lc]; xN[0]=v.x; xN[1]=v.y; xN[2]=v.z; xN[3]=v.w;
        r0C[0] = sbA[1][lr][lc - 1];
        v = *(const float4*)&sbA[1][lr][lc]; r0C[1]=v.x; r0C[2]=v.y; r0C[3]=v.z; r0C[4]=v.w;
        v = *(const float4*)&sbA[1][lr - 1][lc]; r0N[0]=v.x; r0N[1]=v.y; r0N[2]=v.z; r0N[3]=v.w;
        r1C[0] = sbA[2][lr][lc - 1];
        v = *(const float4*)&sbA[2][lr][lc]; r1C[1]=v.x; r1C[2]=v.y; r1C[3]=v.z; r1C[4]=v.w;
        v = *(const float4*)&sbA[2][lr + 1][lc]; r1S[0]=v.x; r1S[1]=v.y; r1S[2]=v.z; r1S[3]=v.w;
    };

    // ---- stage-2 core (shared by phases B and D) ----
    auto s2core = [&](auto SAFE_c, int gi, int gjb,
                      const float* xA, const float* xS, const float* xN,
                      const float* r0C, const float* r0N, const float* r1C, const float* r1S,
                      const float* cu0, const float* cu1, const float* cu2, const float* cu3,
                      float* un0, float* un1, float* un2, float* un3) {
        constexpr bool SAFE = decltype(SAFE_c)::value;
        const bool im0 = SAFE ? true : (gi > 0);
        const bool imH = SAFE ? true : (gi < H - 1);
        #pragma unroll
        for (int e = 0; e < 4; ++e) {
            const int gj = gjb + e;
            const bool jm0 = SAFE ? true : (gj > 0);
            const bool jmW = SAFE ? true : (gj < W - 1);
            const float xC = xA[e + 1], xE = xA[e + 2], xW_ = xA[e];
            const float I0c = (imH ? xS[e + 1] - xC : 0.f) - r0C[e + 1];
            const float I0n = im0 ? (xC - xN[e] - r0N[e]) : 0.f;
            const float I0w = jm0 ? ((imH ? xS[e] - xW_ : 0.f) - r0C[e]) : 0.f;
            const float I1c = (jmW ? xE - xC : 0.f) - r1C[e + 1];
            const float I1w = jm0 ? (xC - xW_ - r1C[e]) : 0.f;
            const float I1s = imH ? ((jmW ? xS[e + 2] - xS[e + 1] : 0.f) - r1S[e]) : 0.f;
            const float g0 = I0c - I0n;
            const float g1 = jm0 ? (I0c - I0w) : 0.f;
            const float g2 = I1c - I1w;
            const float g3 = imH ? (I1s - I1c) : 0.f;
            const float up0 = cu0[e] + SIGMA * g0;
            const float up1 = cu1[e] + SIGMA * g1;
            const float up2 = cu2[e] + SIGMA * g2;
            const float up3 = cu3[e] + SIGMA * g3;
            const float ss  = up0 * up0 + up1 * up1 + up2 * up2 + up3 * up3;
            const float inv = fminf(LAM2 * rsqrtf(ss), 1.f);
            un0[e] = cu0[e] + RHO * (up0 * inv - cu0[e]);
            un1[e] = cu1[e] + RHO * (up1 * inv - cu1[e]);
            un2[e] = cu2[e] + RHO * (up2 * inv - cu2[e]);
            un3[e] = cu3[e] + RHO * (up3 * inv - cu3[e]);
        }
    };

    // ================= phase A: stage-1 of iter k, rows -3..18 =================
    auto phaseA = [&](auto SAFE_c) {
        constexpr bool SAFE = decltype(SAFE_c)::value;
        for (int idx = tid; idx < AR * 18; idx += 256) {
            const int rw = idx / 18, rr = rw - 3;
            const int s  = 4 * (idx - rw * 18) - 4;
            const int gi = i0 + rr, gjb = j0 + s;
            const int p  = cb + gi * W + gjb;
            const bool rowC  = SAFE || ((unsigned)gi < H);
            const bool cMain = SAFE || ((unsigned)gjb < W);
            const bool okC   = rowC && cMain;

            float yv[4], x2c[4], r0c[4], r1c[4];
            if (okC) { *(float4*)yv = *(const float4*)(y + p); }
            else     { yv[0] = yv[1] = yv[2] = yv[3] = 0.f; }

            float t0c[4], t1c[4], t0n[4], t1w[4];
            if (MODE == 0) {
                #pragma unroll
                for (int e = 0; e < 4; ++e) {
                    x2c[e] = yv[e]; r0c[e] = 0.f; r1c[e] = 0.f;
                    t0c[e] = t1c[e] = t0n[e] = t1w[e] = 0.f;
                }
            } else {
                if (okC) {
                    *(float4*)x2c = *(const float4*)(srcX + p);
                    const h8 rv = *(const h8*)(rSrc + 2 * p);
                    #pragma unroll
                    for (int e = 0; e < 4; ++e) {
                        r0c[e] = (float)rv[2 * e];
                        r1c[e] = (float)rv[2 * e + 1];
                    }
                } else {
                    #pragma unroll
                    for (int e = 0; e < 4; ++e) { x2c[e] = 0.f; r0c[e] = 0.f; r1c[e] = 0.f; }
                }
                tGlob(SAFE_c, gi, gjb, p, t0c, t1c, t0n, t1w);
            }

            float xb[4], rb0[4], rb1[4], xn[4], rn0[4], rn1[4];
            prox1(SAFE_c, gi, gjb, yv, x2c, r0c, r1c, t0c, t1c, t0n, t1w,
                  xb, rb0, rb1, xn, rn0, rn1);

            *(float4*)&sbA[0][rr + 3][s + 8] = *(float4*)xb;
            *(float4*)&sbA[1][rr + 3][s + 8] = *(float4*)rb0;
            *(float4*)&sbA[2][rr + 3][s + 8] = *(float4*)rb1;
            if (rr >= -1 && rr <= 16) {
                *(float4*)&sbB[0][rr + 1][s + 4] = *(float4*)xn;
                *(float4*)&sbB[1][rr + 1][s + 4] = *(float4*)rn0;
                *(float4*)&sbB[2][rr + 1][s + 4] = *(float4*)rn1;
            }
            // no global stores: iter-k x/r live only in LDS
        }
    };

    // ================= phase B: stage-2 of iter k, rows -2..17 -> su ===========
    auto phaseB = [&](auto SAFE_c) {
        constexpr bool SAFE = decltype(SAFE_c)::value;
        for (int idx = tid; idx < UR * 18; idx += 256) {
            const int rw = idx / 18, rr = rw - 2;
            const int s  = 4 * (idx - rw * 18) - 4;
            const int gi = i0 + rr, gjb = j0 + s;
            const int p  = cb + gi * W + gjb;

            float xA[6], xS[6], xN[4], r0C[5], r0N[4], r1C[5], r1S[4];
            loadA(rr, s, xA, xS, xN, r0C, r0N, r1C, r1S);

            float cu0[4], cu1[4], cu2[4], cu3[4];
            if (MODE == 0) {
                #pragma unroll
                for (int e = 0; e < 4; ++e) { cu0[e] = cu1[e] = cu2[e] = cu3[e] = 0.f; }
            } else {
                const bool okC = SAFE || (((unsigned)gi < H) && ((unsigned)gjb < W));
                if (okC) {
                    const h8 a = *(const h8*)(uSrc + 4 * p);
                    const h8 b = *(const h8*)(uSrc + 4 * p + 8);
                    cu0[0]=(float)a[0]; cu1[0]=(float)a[1]; cu2[0]=(float)a[2]; cu3[0]=(float)a[3];
                    cu0[1]=(float)a[4]; cu1[1]=(float)a[5]; cu2[1]=(float)a[6]; cu3[1]=(float)a[7];
                    cu0[2]=(float)b[0]; cu1[2]=(float)b[1]; cu2[2]=(float)b[2]; cu3[2]=(float)b[3];
                    cu0[3]=(float)b[4]; cu1[3]=(float)b[5]; cu2[3]=(float)b[6]; cu3[3]=(float)b[7];
                } else {
                    #pragma unroll
                    for (int e = 0; e < 4; ++e) { cu0[e] = cu1[e] = cu2[e] = cu3[e] = 0.f; }
                }
            }

            float un0[4], un1[4], un2[4], un3[4];
            s2core(SAFE_c, gi, gjb, xA, xS, xN, r0C, r0N, r1C, r1S,
                   cu0, cu1, cu2, cu3, un0, un1, un2, un3);

            const int ur = rr + 2, uc = s + 6;
            if constexpr (SAFE) {
                h8 w0, w1;
                #pragma unroll
                for (int e = 0; e < 2; ++e) {
                    w0[4*e+0]=(f16)un0[e]; w0[4*e+1]=(f16)un1[e];
                    w0[4*e+2]=(f16)un2[e]; w0[4*e+3]=(f16)un3[e];
                }
                #pragma unroll
                for (int e = 2; e < 4; ++e) {
                    w1[4*(e-2)+0]=(f16)un0[e]; w1[4*(e-2)+1]=(f16)un1[e];
                    w1[4*(e-2)+2]=(f16)un2[e]; w1[4*(e-2)+3]=(f16)un3[e];
                }
                *(h8*)&su[ur][uc][0]     = w0;
                *(h8*)&su[ur][uc + 2][0] = w1;
            } else {
                // zero-padding semantics: out-of-image pixels MUST store 0
                #pragma unroll
                for (int e = 0; e < 4; ++e) {
                    const int gj = gjb + e;
                    const bool ok = ((unsigned)gi < H) && ((unsigned)gj < W);
                    h4 hv = {};
                    if (ok) { hv[0]=(f16)un0[e]; hv[1]=(f16)un1[e]; hv[2]=(f16)un2[e]; hv[3]=(f16)un3[e]; }
                    *(h4*)&su[ur][uc + e][0] = hv;
                }
            }
        }
    };

    // ================= phase C: stage-1 of iter k+1, rows -1..16 ===============
    auto phaseC = [&](auto SAFE_c) {
        constexpr bool SAFE = decltype(SAFE_c)::value;
        for (int idx = tid; idx < BR * 18; idx += 256) {
            const int rw = idx / 18, rr = rw - 1;
            const int s  = 4 * (idx - rw * 18) - 4;
            const int gi = i0 + rr, gjb = j0 + s;
            const int p  = cb + gi * W + gjb;
            const bool okC = SAFE || (((unsigned)gi < H) && ((unsigned)gjb < W));

            float yv[4];
            if (okC) { *(float4*)yv = *(const float4*)(y + p); }
            else     { yv[0] = yv[1] = yv[2] = yv[3] = 0.f; }

            float x2c[4], r0c[4], r1c[4];
            *(float4*)x2c = *(const float4*)&sbB[0][rr + 1][s + 4];
            *(float4*)r0c = *(const float4*)&sbB[1][rr + 1][s + 4];
            *(float4*)r1c = *(const float4*)&sbB[2][rr + 1][s + 4];

            // u_k gather from LDS (rows rr-1..rr+1 -> su rows rr+1..rr+3)
            h4 pN_[6], pC_[6], pS_[4];
            #pragma unroll
            for (int k = 0; k < 6; ++k) {
                pN_[k] = *(const h4*)&su[rr + 1][s + 5 + k][0];
                pC_[k] = *(const h4*)&su[rr + 2][s + 5 + k][0];
            }
            #pragma unroll
            for (int k = 0; k < 4; ++k)
                pS_[k] = *(const h4*)&su[rr + 3][s + 6 + k][0];

            const float u0c[4] = {(float)pC_[1][0], (float)pC_[2][0], (float)pC_[3][0], (float)pC_[4][0]};
            const float u1c[5] = {(float)pC_[1][1], (float)pC_[2][1], (float)pC_[3][1], (float)pC_[4][1], (float)pC_[5][1]};
            const float u2r[6] = {(float)pC_[0][2], (float)pC_[1][2], (float)pC_[2][2], (float)pC_[3][2], (float)pC_[4][2], (float)pC_[5][2]};
            const float u3c[5] = {(float)pC_[0][3], (float)pC_[1][3], (float)pC_[2][3], (float)pC_[3][3], (float)pC_[4][3]};
            const float u0n[4] = {(float)pN_[1][0], (float)pN_[2][0], (float)pN_[3][0], (float)pN_[4][0]};
            const float u1n[5] = {(float)pN_[1][1], (float)pN_[2][1], (float)pN_[3][1], (float)pN_[4][1], (float)pN_[5][1]};
            const float u3n[5] = {(float)pN_[0][3], (float)pN_[1][3], (float)pN_[2][3], (float)pN_[3][3], (float)pN_[4][3]};
            const float u0s[4] = {(float)pS_[0][0], (float)pS_[1][0], (float)pS_[2][0], (float)pS_[3][0]};

            float t0c[4], t1c[4], t0n[4], t1w[4];
            if constexpr (SAFE) {
                #pragma unroll
                for (int e = 0; e < 4; ++e) {
                    t0c[e] = TAU * (u0c[e] - u0s[e] + u1c[e] - u1c[e + 1]);
                    t1c[e] = TAU * (u2r[e + 1] - u2r[e + 2] + u3n[e + 1] - u3c[e + 1]);
                    t0n[e] = TAU * (u0n[e] - u0c[e] + u1n[e] - u1n[e + 1]);
                    t1w[e] = TAU * (u2r[e] - u2r[e + 1] + u3n[e] - u3c[e]);
                }
            } else {
                const bool im0 = gi > 0, imHl = gi < H - 1;
                #pragma unroll
                for (int e = 0; e < 4; ++e) {
                    const int gj = gjb + e;
                    const bool jm0 = gj > 0;
                    t0c[e] = TAU * (u0c[e] - u0s[e] + (jm0 ? u1c[e] : 0.f) - u1c[e + 1]);
                    t1c[e] = TAU * (u2r[e + 1] - u2r[e + 2] + u3n[e + 1] - (imHl ? u3c[e + 1] : 0.f));
                    t0n[e] = im0 ? TAU * (u0n[e] - u0c[e] + (jm0 ? u1n[e] : 0.f) - u1n[e + 1]) : 0.f;
                    t1w[e] = jm0 ? TAU * (u2r[e] - u2r[e + 1] + u3n[e] - (imHl ? u3c[e] : 0.f)) : 0.f;
                }
            }

            float xb[4], rb0[4], rb1[4], xn[4], rn0[4], rn1[4];
            prox1(SAFE_c, gi, gjb, yv, x2c, r0c, r1c, t0c, t1c, t0n, t1w,
                  xb, rb0, rb1, xn, rn0, rn1);

            *(float4*)&sbA[0][rr + 3][s + 8] = *(float4*)xb;
            *(float4*)&sbA[1][rr + 3][s + 8] = *(float4*)rb0;
            *(float4*)&sbA[2][rr + 3][s + 8] = *(float4*)rb1;

            if ((unsigned)rr < 16 && (unsigned)s < 64) { // interior strip
                if (MODE == 2) {
                    *(float4*)(outp + p) = *(float4*)xn;
                    *(float4*)(outp + CHW + 2 * p)     = make_float4(rn0[0], rn1[0], rn0[1], rn1[1]);
                    *(float4*)(outp + CHW + 2 * p + 4) = make_float4(rn0[2], rn1[2], rn0[3], rn1[3]);
                } else {
                    *(float4*)(dstX + p) = *(float4*)xn;
                    h8 hr;
                    #pragma unroll
                    for (int e = 0; e < 4; ++e) {
                        hr[2 * e]     = (f16)rn0[e];
                        hr[2 * e + 1] = (f16)rn1[e];
                    }
                    *(h8*)(rDst + 2 * p) = hr;
                }
            }
        }
    };

    // ---- run phases (sbA WAR hazards covered by the inter-phase barriers) ----
    if (!edge) phaseA(std::true_type{});  else phaseA(std::false_type{});
    __syncthreads();
    if (!edge) phaseB(std::true_type{});  else phaseB(std::false_type{});
    __syncthreads();
    if (!edge) phaseC(std::true_type{});  else phaseC(std::false_type{});
    __syncthreads();

    // ================= phase D: stage-2 of iter k+1, interior ==================
    {
        const int rr = tid >> 4;
        const int s  = 4 * (tid & 15);
        const int gi = i0 + rr, gjb = j0 + s;
        const int p  = cb + gi * W + gjb;

        float xA[6], xS[6], xN[4], r0C[5], r0N[4], r1C[5], r1S[4];
        loadA(rr, s, xA, xS, xN, r0C, r0N, r1C, r1S);

        float cu0[4], cu1[4], cu2[4], cu3[4];
        {
            const h8 a = *(const h8*)&su[rr + 2][s + 6][0];
            const h8 b = *(const h8*)&su[rr + 2][s + 8][0];
            cu0[0]=(float)a[0]; cu1[0]=(float)a[1]; cu2[0]=(float)a[2]; cu3[0]=(float)a[3];
            cu0[1]=(float)a[4]; cu1[1]=(float)a[5]; cu2[1]=(float)a[6]; cu3[1]=(float)a[7];
            cu0[2]=(float)b[0]; cu1[2]=(float)b[1]; cu2[2]=(float)b[2]; cu3[2]=(float)b[3];
            cu0[3]=(float)b[4]; cu1[3]=(float)b[5]; cu2[3]=(float)b[6]; cu3[3]=(float)b[7];
        }

        float un0[4], un1[4], un2[4], un3[4];
        if (!edge)
            s2core(std::true_type{},  gi, gjb, xA, xS, xN, r0C, r0N, r1C, r1S,
                   cu0, cu1, cu2, cu3, un0, un1, un2, un3);
        else
            s2core(std::false_type{}, gi, gjb, xA, xS, xN, r0C, r0N, r1C, r1S,
                   cu0, cu1, cu2, cu3, un0, un1, un2, un3);

        if (MODE == 2) {
            #pragma unroll
            for (int e = 0; e < 4; ++e)
                *(float4*)(outp + 3 * CHW + 4 * (p + e)) =
                    make_float4(un0[e], un1[e], un2[e], un3[e]);
        } else {
            h8 w0, w1;
            #pragma unroll
            for (int e = 0; e < 2; ++e) {
                w0[4*e+0]=(f16)un0[e]; w0[4*e+1]=(f16)un1[e];
                w0[4*e+2]=(f16)un2[e]; w0[4*e+3]=(f16)un3[e];
            }
            #pragma unroll
            for (int e = 2; e < 4; ++e) {
                w1[4*(e-2)+0]=(f16)un0[e]; w1[4*(e-2)+1]=(f16)un1[e];
                w1[4*(e-2)+2]=(f16)un2[e]; w1[4*(e-2)+3]=(f16)un3[e];
            }
            *(h8*)(uDst + 4 * p)     = w0;
            *(h8*)(uDst + 4 * p + 8) = w1;
        }
    }
}

extern "C" void kernel_launch(void* const* d_in, const int* in_sizes, int n_in,
                              void* d_out, int out_size, void* d_ws, size_t ws_size,
                              hipStream_t stream) {
    const float* y = (const float*)d_in[0];
    float* out = (float*)d_out;

    // ws layout: x2 fp32 buf0 | x2 fp32 buf1 | h-buf0 (6*CHW f16) | h-buf1
    float* x0 = (float*)d_ws;
    float* x1 = x0 + CHW;
    f16*   h0 = (f16*)(x1 + CHW);
    f16*   h1 = h0 + 6 * CHW;

    dim3 blk(256, 1, 1);
    dim3 grd(W / TW, H / TH, C);    // (8, 32, 3) = 768 blocks

    // 15 fused launches: pairs (1,2),(3,4),...,(29,30)
    fused2<0><<<grd, blk, 0, stream>>>(y, nullptr, nullptr, x0, h0, nullptr);
    for (int i = 1; i < NPAIR - 1; ++i) {
        const bool even = (i % 2 == 0);
        float* sx = even ? x1 : x0;  f16* sh = even ? h1 : h0;
        float* dx = even ? x0 : x1;  f16* dh = even ? h0 : h1;
        fused2<1><<<grd, blk, 0, stream>>>(y, sx, sh, dx, dh, nullptr);
    }
    // pair 15 (iters 29,30): src = dst of pair 14 (i=13, odd -> x1/h1)
    fused2<2><<<grd, blk, 0, stream>>>(y, x1, h1, nullptr, nullptr, out);
}